// Round 10
// baseline (980.118 us; speedup 1.0000x reference)
//
#include <hip/hip_runtime.h>

#define L1_BINS 4096          // top 12 bits of 22-bit fixed-point key
#define L1_UINTS 2048         // packed pairs (16-bit counts)
#define L2_BINS 1024          // low 10 bits
#define KEY_MAX 4194303u      // 2^22 - 1
#define NH2_BLOCKS 2048
#define NMG_BLOCKS 256
#define NREF_BLOCKS 2048
#define NBIN_BLOCKS 2048
#define NW (NBIN_BLOCKS * 4)  // per-wave partial slots

struct Ranks { unsigned int r[32]; };
struct Fracs { float f[16]; };

__device__ __forceinline__ unsigned int wave_iscan(unsigned int s, int lane) {
  unsigned int inc = s;
#pragma unroll
  for (int d = 1; d < 64; d <<= 1) {
    unsigned int u = __shfl_up(inc, d);
    if (lane >= d) inc += u;
  }
  return inc;
}

// ---------------- Kernel 1: LDS-staged rows; thread-per-row; no shuffles ---
__global__ __launch_bounds__(256, 4) void k_h2(const float4* __restrict__ lg4,
                                               const int* __restrict__ labels,
                                               unsigned int* __restrict__ keys,
                                               unsigned int* __restrict__ histg,
                                               unsigned int* __restrict__ dones,
                                               int n) {
  __shared__ float stage[256 * 20];   // 256 rows x (16 floats + 4 pad) = 20KB
  __shared__ unsigned int lh[L1_UINTS];
  for (int i = threadIdx.x; i < L1_UINTS; i += 256) lh[i] = 0u;
  if (blockIdx.x == 0 && threadIdx.x < 3) dones[threadIdx.x] = 0u;
  int nchunks = (n + 255) >> 8;
  for (int c = blockIdx.x; c < nchunks; c += gridDim.x) {
    __syncthreads();  // protect stage from previous iteration's readers
#pragma unroll
    for (int k = 0; k < 4; ++k) {
      int f = threadIdx.x + k * 256;            // float4 index within chunk
      long gi = (long)c * 1024 + f;
      if (gi < (long)n * 4) {
        float4 v = lg4[gi];
        int r = f >> 2, q = f & 3;
        *reinterpret_cast<float4*>(&stage[r * 20 + q * 4]) = v;
      }
    }
    __syncthreads();
    int row = c * 256 + threadIdx.x;
    if (row < n) {
      const float* rp = &stage[threadIdx.x * 20];
      float4 a = *reinterpret_cast<const float4*>(rp);
      float4 b = *reinterpret_cast<const float4*>(rp + 4);
      float4 cc = *reinterpret_cast<const float4*>(rp + 8);
      float4 d = *reinterpret_cast<const float4*>(rp + 12);
      float l[16] = {a.x, a.y, a.z, a.w, b.x, b.y, b.z, b.w,
                     cc.x, cc.y, cc.z, cc.w, d.x, d.y, d.z, d.w};
      float m = l[0]; int am = 0;
#pragma unroll
      for (int j = 1; j < 16; ++j) { bool g = l[j] > m; m = g ? l[j] : m; am = g ? j : am; }
      float Z = 0.f, S2 = 0.f;
#pragma unroll
      for (int j = 0; j < 16; ++j) { float e = __expf(l[j] - m); Z += e; S2 += e * e; }
      float r_ = S2 / (Z * Z) + 1e-12f;
      float h2 = -__log2f(r_);
      int ki = (int)(h2 * 1048576.0f);
      unsigned int key = (unsigned int)min(max(ki, 0), (int)KEY_MAX);
      keys[row] = key | ((am != labels[row]) ? 0x80000000u : 0u);
      atomicAdd(&lh[key >> 11], ((key >> 10) & 1u) ? 65536u : 1u);
    }
  }
  __syncthreads();
  unsigned int* dst = histg + (size_t)blockIdx.x * L1_UINTS;
  for (int i = threadIdx.x; i < L1_UINTS; i += 256) dst[i] = lh[i];
}

// ---------------- Kernel 2: merge hists; last block does select-L1 ---------
__global__ __launch_bounds__(256) void k_merge(const unsigned int* __restrict__ histg,
                                               unsigned int* __restrict__ merged,
                                               unsigned int* __restrict__ hist2,
                                               unsigned int* __restrict__ dones,
                                               unsigned int* __restrict__ selpfx,
                                               unsigned int* __restrict__ selrank,
                                               Ranks rk) {
  __shared__ unsigned int slo[32][9], shi[32][9];
  __shared__ unsigned int is_last;
  for (int i = threadIdx.x; i < 128; i += 256)
    hist2[blockIdx.x * 128 + i] = 0u;
  int col0 = blockIdx.x * 8;
  int c = threadIdx.x & 7;
  int rg = threadIdx.x >> 3;
  unsigned int alo = 0, ahi = 0;
  for (int r = rg; r < NH2_BLOCKS; r += 32) {
    unsigned int v = histg[(size_t)r * L1_UINTS + col0 + c];
    alo += v & 0xFFFFu;
    ahi += v >> 16;
  }
  slo[rg][c] = alo;
  shi[rg][c] = ahi;
  __syncthreads();
  if (threadIdx.x < 8) {
    unsigned int lo = 0, hi = 0;
#pragma unroll
    for (int g = 0; g < 32; ++g) { lo += slo[g][threadIdx.x]; hi += shi[g][threadIdx.x]; }
    int pc = col0 + threadIdx.x;
    merged[2 * pc] = lo;
    merged[2 * pc + 1] = hi;
  }
  __threadfence();
  __syncthreads();
  if (threadIdx.x == 0)
    is_last = (atomicAdd(&dones[0], 1u) == (unsigned int)gridDim.x - 1u) ? 1u : 0u;
  __syncthreads();
  if (!is_last) return;
  __threadfence();
  int wid = threadIdx.x >> 6, lane = threadIdx.x & 63;
  for (int j = wid; j < 32; j += 4) {
    unsigned int rem = rk.r[j];
    const unsigned int* mp = merged + lane * 64;
    unsigned int s = 0;
#pragma unroll 8
    for (int t = 0; t < 64; ++t) s += mp[t];
    unsigned int inc = wave_iscan(s, lane);
    unsigned int ex = inc - s;
    bool own = (rem >= ex) && (rem < ex + s);
    int src = __ffsll((long long)__ballot(own)) - 1;
    rem -= __shfl(ex, src);
    int base = src * 64;
    unsigned int v2 = merged[base + lane];
    unsigned int inc2 = wave_iscan(v2, lane);
    unsigned int ex2 = inc2 - v2;
    bool own2 = (rem >= ex2) && (rem < ex2 + v2);
    int s2 = __ffsll((long long)__ballot(own2)) - 1;
    unsigned int ex2s = __shfl(ex2, s2);
    if (lane == 0) {
      selpfx[j] = (unsigned int)(base + s2);
      selrank[j] = rem - ex2s;
    }
  }
}

// ---------------- Kernel 3: refine via LDS bin-map; last block select-L2 ---
__global__ __launch_bounds__(256) void k_refine(const unsigned int* __restrict__ keys,
                                                const unsigned int* __restrict__ selpfx,
                                                unsigned int* __restrict__ hist2,
                                                unsigned int* __restrict__ dones,
                                                unsigned int* __restrict__ selrank,
                                                unsigned int* __restrict__ vout,
                                                int n) {
  __shared__ unsigned char selmap[L1_BINS];
  __shared__ unsigned int sp[32];
  __shared__ unsigned int is_last;
  for (int i = threadIdx.x; i < L1_BINS; i += 256) selmap[i] = 0xFF;
  if (threadIdx.x < 32) sp[threadIdx.x] = selpfx[threadIdx.x];
  __syncthreads();
  if (threadIdx.x == 0) {
    for (int j = 31; j >= 0; --j) selmap[sp[j]] = (unsigned char)j;  // lowest j wins
  }
  __syncthreads();
  int stride = gridDim.x * blockDim.x;
  for (int i = blockIdx.x * blockDim.x + threadIdx.x; i < n; i += stride) {
    unsigned int key = keys[i] & KEY_MAX;
    unsigned int c = selmap[key >> 10];
    if (c != 0xFFu) atomicAdd(&hist2[(int)c * L2_BINS + (int)(key & (L2_BINS - 1))], 1u);
  }
  __threadfence();
  __syncthreads();
  if (threadIdx.x == 0)
    is_last = (atomicAdd(&dones[1], 1u) == (unsigned int)gridDim.x - 1u) ? 1u : 0u;
  __syncthreads();
  if (!is_last) return;
  __threadfence();
  int wid = threadIdx.x >> 6, lane = threadIdx.x & 63;
  for (int j = wid; j < 32; j += 4) {
    unsigned int rem = selrank[j];
    unsigned int canon = selmap[sp[j]];
    const unsigned int* h = hist2 + (int)canon * L2_BINS;
    unsigned int s = 0;
#pragma unroll
    for (int t = 0; t < 16; ++t) s += h[lane * 16 + t];
    unsigned int inc = wave_iscan(s, lane);
    unsigned int ex = inc - s;
    bool own = (rem >= ex) && (rem < ex + s);
    int src = __ffsll((long long)__ballot(own)) - 1;
    rem -= __shfl(ex, src);
    unsigned int v2 = (lane < 16) ? h[src * 16 + lane] : 0u;
    unsigned int inc2 = wave_iscan(v2, lane);
    unsigned int ex2 = inc2 - v2;
    bool own2 = (lane < 16) && (rem >= ex2) && (rem < ex2 + v2);
    int s2 = __ffsll((long long)__ballot(own2)) - 1;
    if (lane == 0)
      vout[j] = (sp[j] << 10) | (unsigned int)(src * 16 + s2);  // 22-bit key
  }
}

// ---------------- Kernel 4: named-scalar accumulators (spill-proof) -------
// partials: [(bin*3+comp)][wave]; comp 0=cnt|err<<16, 1=sum(key&2047), 2=sum(key>>11)
__global__ __launch_bounds__(256, 4) void k_bin(const unsigned int* __restrict__ keys,
                                                const unsigned int* __restrict__ vp,
                                                unsigned int* __restrict__ partials,
                                                unsigned int* __restrict__ dones,
                                                float* __restrict__ out, int n,
                                                Fracs fr) {
  __shared__ unsigned int sT[16];
  __shared__ unsigned int is_last;
  if (threadIdx.x < 16) {
    int i = threadIdx.x;
    float lo = (float)(vp[2 * i] + 1u) * 0x1p-20f;   // exact
    float hi = (float)(vp[2 * i + 1] + 1u) * 0x1p-20f;
    float f = fr.f[i];
    float e = lo * (1.0f - f) + hi * f;
    if (i == 15) e += 1e-6f;
    // T = smallest key with (key+0.5)*2^-20 > e
    double kd = (double)e * 1048576.0 - 0.5;
    int T = (int)floor(kd) + 1;
    while (T > 0 && ((float)(T - 1) + 0.5f) * 0x1p-20f > e) --T;
    while (((float)T + 0.5f) * 0x1p-20f <= e) ++T;
    sT[i] = (unsigned int)T;
  }
  __syncthreads();
  unsigned int tT[16];
#pragma unroll
  for (int j = 0; j < 16; ++j) tT[j] = sT[j];

#define DECL(b) unsigned int ce_##b = 0u; unsigned long long kk_##b = 0ull;
  DECL(0) DECL(1) DECL(2) DECL(3) DECL(4) DECL(5) DECL(6) DECL(7)
  DECL(8) DECL(9) DECL(10) DECL(11) DECL(12) DECL(13) DECL(14)
#undef DECL

  int stride = gridDim.x * 256;
  for (int i = blockIdx.x * 256 + threadIdx.x; i < n; i += stride) {
    unsigned int kp = keys[i];
    unsigned int key = kp & KEY_MAX;
    unsigned int cev = 1u | ((kp >> 31) << 16);
    unsigned long long kkv =
        ((unsigned long long)(key >> 11) << 32) | (unsigned long long)(key & 2047u);
    int less = 0;
#pragma unroll
    for (int j = 0; j < 16; ++j) less += (key >= tT[j]) ? 1 : 0;
    int bin = less - 1;  // valid 0..14
#define STEP(b) if (bin == (b)) { ce_##b += cev; kk_##b += kkv; }
    STEP(0) STEP(1) STEP(2) STEP(3) STEP(4) STEP(5) STEP(6) STEP(7)
    STEP(8) STEP(9) STEP(10) STEP(11) STEP(12) STEP(13) STEP(14)
#undef STEP
  }

  int wid = threadIdx.x >> 6, lane = threadIdx.x & 63;
  int wslot = blockIdx.x * 4 + wid;
#define RED(b) { unsigned int ce = ce_##b; unsigned long long kk = kk_##b;      \
    for (int off = 32; off > 0; off >>= 1) {                                     \
      ce += __shfl_xor(ce, off);                                                 \
      kk += __shfl_xor(kk, off);                                                 \
    }                                                                            \
    if (lane == 0) {                                                             \
      partials[((b) * 3 + 0) * NW + wslot] = ce;                                 \
      partials[((b) * 3 + 1) * NW + wslot] = (unsigned int)(kk & 0xFFFFFFFFull); \
      partials[((b) * 3 + 2) * NW + wslot] = (unsigned int)(kk >> 32);           \
    } }
  RED(0) RED(1) RED(2) RED(3) RED(4) RED(5) RED(6) RED(7)
  RED(8) RED(9) RED(10) RED(11) RED(12) RED(13) RED(14)
#undef RED

  __threadfence();
  __syncthreads();
  if (threadIdx.x == 0)
    is_last = (atomicAdd(&dones[2], 1u) == (unsigned int)gridDim.x - 1u) ? 1u : 0u;
  __syncthreads();
  if (is_last && threadIdx.x < 64) {
    __threadfence();
    int l = threadIdx.x;
    float g = 0.f;
    for (int b = 0; b < 15; ++b) {
      double cd = 0.0, ed = 0.0, kd = 0.0;
      for (int w = l; w < NW; w += 64) {
        unsigned int ce = partials[(b * 3 + 0) * NW + w];
        unsigned int kl = partials[(b * 3 + 1) * NW + w];
        unsigned int kh = partials[(b * 3 + 2) * NW + w];
        cd += (double)(ce & 0xFFFFu);
        ed += (double)(ce >> 16);
        kd += (double)kh * 2048.0 + (double)kl;
      }
      for (int off = 32; off > 0; off >>= 1) {
        cd += __shfl_xor(cd, off);
        ed += __shfl_xor(ed, off);
        kd += __shfl_xor(kd, off);
      }
      if (l == 0) {
        double safe = cd > 1.0 ? cd : 1.0;
        float u = (float)(((kd + 0.5 * cd) * (1.0 / 1048576.0)) / safe);
        float eb = (float)(ed / safe);
        float inner = 2.0f * exp2f(-u) - 1.0f;
        float s = (inner > 0.f) ? sqrtf(inner) : 0.f;
        float risk = 0.5f * (1.0f - s);
        g += (cd > 0.0) ? fabsf(eb - risk) : 0.f;
      }
    }
    if (l == 0) out[0] = g * (1.0f / 15.0f);
  }
}

extern "C" void kernel_launch(void* const* d_in, const int* in_sizes, int n_in,
                              void* d_out, int out_size, void* d_ws, size_t ws_size,
                              hipStream_t stream) {
  const float* logits = (const float*)d_in[0];
  const int* labels = (const int*)d_in[1];
  float* out = (float*)d_out;
  int n = in_sizes[1];  // labels count = number of rows

  char* ws = (char*)d_ws;
  size_t offKeys = 0;                                             // n*4 = 16MB
  size_t offHg = (size_t)n * 4;                                   // 2048*2048*4 = 16MB
  size_t offMerged = offHg + (size_t)NH2_BLOCKS * L1_UINTS * 4;   // 4096*4
  size_t offH2b = offMerged + (size_t)L1_BINS * 4;                // 32*1024*4
  size_t offDone = offH2b + (size_t)32 * L2_BINS * 4;             // 16B
  size_t offSelP = offDone + 16;                                  // 32*4
  size_t offSelR = offSelP + 128;                                 // 32*4
  size_t offV = offSelR + 128;                                    // 32*4
  size_t offPart = (offV + 128 + 255) & ~(size_t)255;             // 45*NW*4

  unsigned int* keys = (unsigned int*)(ws + offKeys);
  unsigned int* histg = (unsigned int*)(ws + offHg);
  unsigned int* merged = (unsigned int*)(ws + offMerged);
  unsigned int* hist2 = (unsigned int*)(ws + offH2b);
  unsigned int* dones = (unsigned int*)(ws + offDone);
  unsigned int* selp = (unsigned int*)(ws + offSelP);
  unsigned int* selr = (unsigned int*)(ws + offSelR);
  unsigned int* vp = (unsigned int*)(ws + offV);
  unsigned int* part = (unsigned int*)(ws + offPart);

  // host-side quantile positions (f32, matching jnp.linspace/quantile math)
  Ranks rk;
  Fracs fr;
  float nm1 = (float)(n - 1);
  for (int i = 0; i < 16; ++i) {
    float q = (i == 15) ? 1.0f : (float)i * (1.0f / 15.0f);
    float idxf = q * nm1;
    float flo = floorf(idxf);
    unsigned int klo = (unsigned int)flo;
    unsigned int khi = (unsigned int)ceilf(idxf);
    unsigned int maxi = (unsigned int)(n - 1);
    if (klo > maxi) klo = maxi;
    if (khi > maxi) khi = maxi;
    rk.r[2 * i] = klo;
    rk.r[2 * i + 1] = khi;
    fr.f[i] = idxf - flo;
  }

  // 1) keys + per-block L1 hists (also zeroes done counters)
  k_h2<<<NH2_BLOCKS, 256, 0, stream>>>((const float4*)logits, labels, keys, histg, dones, n);
  // 2) merge hists; zero hist2; last block -> select L1 (12 bits)
  k_merge<<<NMG_BLOCKS, 256, 0, stream>>>(histg, merged, hist2, dones, selp, selr, rk);
  // 3) refine low 10 bits via LDS bin-map; last block -> select L2
  k_refine<<<NREF_BLOCKS, 256, 0, stream>>>(keys, selp, hist2, dones, selr, vp, n);
  // 4) named-scalar integer binning + fused final
  k_bin<<<NBIN_BLOCKS, 256, 0, stream>>>(keys, vp, part, dones, out, n, fr);

  (void)n_in; (void)out_size; (void)ws_size;
}

// Round 11
// 432.890 us; speedup vs baseline: 2.2641x; 2.2641x over previous
//
#include <hip/hip_runtime.h>

#define L1_BINS 4096          // top 12 bits of 22-bit fixed-point key
#define L1_UINTS 2048         // packed pairs (16-bit counts)
#define L2_BINS 1024          // low 10 bits
#define KEY_MAX 4194303u      // 2^22 - 1
#define NH2_BLOCKS 2048
#define NMG_BLOCKS 256
#define NREF_BLOCKS 2048
#define NBIN_BLOCKS 1024

struct Ranks { unsigned int r[32]; };
struct Fracs { float f[16]; };

__device__ __forceinline__ unsigned int wave_iscan(unsigned int s, int lane) {
  unsigned int inc = s;
#pragma unroll
  for (int d = 1; d < 64; d <<= 1) {
    unsigned int u = __shfl_up(inc, d);
    if (lane >= d) inc += u;
  }
  return inc;
}

// ---------------- Kernel 1: LDS-staged rows; thread-per-row; no shuffles ---
__global__ __launch_bounds__(256, 4) void k_h2(const float4* __restrict__ lg4,
                                               const int* __restrict__ labels,
                                               unsigned int* __restrict__ keys,
                                               unsigned int* __restrict__ histg,
                                               unsigned int* __restrict__ dones,
                                               int n) {
  __shared__ float stage[256 * 20];   // 256 rows x (16 floats + 4 pad) = 20KB
  __shared__ unsigned int lh[L1_UINTS];
  for (int i = threadIdx.x; i < L1_UINTS; i += 256) lh[i] = 0u;
  if (blockIdx.x == 0 && threadIdx.x < 3) dones[threadIdx.x] = 0u;
  int nchunks = (n + 255) >> 8;
  for (int c = blockIdx.x; c < nchunks; c += gridDim.x) {
    __syncthreads();  // protect stage from previous iteration's readers
#pragma unroll
    for (int k = 0; k < 4; ++k) {
      int f = threadIdx.x + k * 256;            // float4 index within chunk
      long gi = (long)c * 1024 + f;
      if (gi < (long)n * 4) {
        float4 v = lg4[gi];
        int r = f >> 2, q = f & 3;
        *reinterpret_cast<float4*>(&stage[r * 20 + q * 4]) = v;
      }
    }
    __syncthreads();
    int row = c * 256 + threadIdx.x;
    if (row < n) {
      const float* rp = &stage[threadIdx.x * 20];
      float4 a = *reinterpret_cast<const float4*>(rp);
      float4 b = *reinterpret_cast<const float4*>(rp + 4);
      float4 cc = *reinterpret_cast<const float4*>(rp + 8);
      float4 d = *reinterpret_cast<const float4*>(rp + 12);
      float l[16] = {a.x, a.y, a.z, a.w, b.x, b.y, b.z, b.w,
                     cc.x, cc.y, cc.z, cc.w, d.x, d.y, d.z, d.w};
      float m = l[0]; int am = 0;
#pragma unroll
      for (int j = 1; j < 16; ++j) { bool g = l[j] > m; m = g ? l[j] : m; am = g ? j : am; }
      float Z = 0.f, S2 = 0.f;
#pragma unroll
      for (int j = 0; j < 16; ++j) { float e = __expf(l[j] - m); Z += e; S2 += e * e; }
      float r_ = S2 / (Z * Z) + 1e-12f;
      float h2 = -__log2f(r_);
      int ki = (int)(h2 * 1048576.0f);
      unsigned int key = (unsigned int)min(max(ki, 0), (int)KEY_MAX);
      keys[row] = key | ((am != labels[row]) ? 0x80000000u : 0u);
      atomicAdd(&lh[key >> 11], ((key >> 10) & 1u) ? 65536u : 1u);
    }
  }
  __syncthreads();
  unsigned int* dst = histg + (size_t)blockIdx.x * L1_UINTS;
  for (int i = threadIdx.x; i < L1_UINTS; i += 256) dst[i] = lh[i];
}

// ---------------- Kernel 2: merge hists; last block does select-L1 ---------
__global__ __launch_bounds__(256) void k_merge(const unsigned int* __restrict__ histg,
                                               unsigned int* __restrict__ merged,
                                               unsigned int* __restrict__ hist2,
                                               unsigned int* __restrict__ dones,
                                               unsigned int* __restrict__ selpfx,
                                               unsigned int* __restrict__ selrank,
                                               Ranks rk) {
  __shared__ unsigned int slo[32][9], shi[32][9];
  __shared__ unsigned int is_last;
  for (int i = threadIdx.x; i < 128; i += 256)
    hist2[blockIdx.x * 128 + i] = 0u;
  int col0 = blockIdx.x * 8;
  int c = threadIdx.x & 7;
  int rg = threadIdx.x >> 3;
  unsigned int alo = 0, ahi = 0;
  for (int r = rg; r < NH2_BLOCKS; r += 32) {
    unsigned int v = histg[(size_t)r * L1_UINTS + col0 + c];
    alo += v & 0xFFFFu;
    ahi += v >> 16;
  }
  slo[rg][c] = alo;
  shi[rg][c] = ahi;
  __syncthreads();
  if (threadIdx.x < 8) {
    unsigned int lo = 0, hi = 0;
#pragma unroll
    for (int g = 0; g < 32; ++g) { lo += slo[g][threadIdx.x]; hi += shi[g][threadIdx.x]; }
    int pc = col0 + threadIdx.x;
    merged[2 * pc] = lo;
    merged[2 * pc + 1] = hi;
  }
  __threadfence();
  __syncthreads();
  if (threadIdx.x == 0)
    is_last = (atomicAdd(&dones[0], 1u) == (unsigned int)gridDim.x - 1u) ? 1u : 0u;
  __syncthreads();
  if (!is_last) return;
  __threadfence();
  int wid = threadIdx.x >> 6, lane = threadIdx.x & 63;
  for (int j = wid; j < 32; j += 4) {
    unsigned int rem = rk.r[j];
    const unsigned int* mp = merged + lane * 64;
    unsigned int s = 0;
#pragma unroll 8
    for (int t = 0; t < 64; ++t) s += mp[t];
    unsigned int inc = wave_iscan(s, lane);
    unsigned int ex = inc - s;
    bool own = (rem >= ex) && (rem < ex + s);
    int src = __ffsll((long long)__ballot(own)) - 1;
    rem -= __shfl(ex, src);
    int base = src * 64;
    unsigned int v2 = merged[base + lane];
    unsigned int inc2 = wave_iscan(v2, lane);
    unsigned int ex2 = inc2 - v2;
    bool own2 = (rem >= ex2) && (rem < ex2 + v2);
    int s2 = __ffsll((long long)__ballot(own2)) - 1;
    unsigned int ex2s = __shfl(ex2, s2);
    if (lane == 0) {
      selpfx[j] = (unsigned int)(base + s2);
      selrank[j] = rem - ex2s;
    }
  }
}

// ---------------- Kernel 3: refine via LDS bin-map; last block select-L2 ---
__global__ __launch_bounds__(256) void k_refine(const unsigned int* __restrict__ keys,
                                                const unsigned int* __restrict__ selpfx,
                                                unsigned int* __restrict__ hist2,
                                                unsigned int* __restrict__ dones,
                                                unsigned int* __restrict__ selrank,
                                                unsigned int* __restrict__ vout,
                                                int n) {
  __shared__ unsigned char selmap[L1_BINS];
  __shared__ unsigned int sp[32];
  __shared__ unsigned int is_last;
  for (int i = threadIdx.x; i < L1_BINS; i += 256) selmap[i] = 0xFF;
  if (threadIdx.x < 32) sp[threadIdx.x] = selpfx[threadIdx.x];
  __syncthreads();
  if (threadIdx.x == 0) {
    for (int j = 31; j >= 0; --j) selmap[sp[j]] = (unsigned char)j;  // lowest j wins
  }
  __syncthreads();
  int stride = gridDim.x * blockDim.x;
  for (int i = blockIdx.x * blockDim.x + threadIdx.x; i < n; i += stride) {
    unsigned int key = keys[i] & KEY_MAX;
    unsigned int c = selmap[key >> 10];
    if (c != 0xFFu) atomicAdd(&hist2[(int)c * L2_BINS + (int)(key & (L2_BINS - 1))], 1u);
  }
  __threadfence();
  __syncthreads();
  if (threadIdx.x == 0)
    is_last = (atomicAdd(&dones[1], 1u) == (unsigned int)gridDim.x - 1u) ? 1u : 0u;
  __syncthreads();
  if (!is_last) return;
  __threadfence();
  int wid = threadIdx.x >> 6, lane = threadIdx.x & 63;
  for (int j = wid; j < 32; j += 4) {
    unsigned int rem = selrank[j];
    unsigned int canon = selmap[sp[j]];
    const unsigned int* h = hist2 + (int)canon * L2_BINS;
    unsigned int s = 0;
#pragma unroll
    for (int t = 0; t < 16; ++t) s += h[lane * 16 + t];
    unsigned int inc = wave_iscan(s, lane);
    unsigned int ex = inc - s;
    bool own = (rem >= ex) && (rem < ex + s);
    int src = __ffsll((long long)__ballot(own)) - 1;
    rem -= __shfl(ex, src);
    unsigned int v2 = (lane < 16) ? h[src * 16 + lane] : 0u;
    unsigned int inc2 = wave_iscan(v2, lane);
    unsigned int ex2 = inc2 - v2;
    bool own2 = (lane < 16) && (rem >= ex2) && (rem < ex2 + v2);
    int s2 = __ffsll((long long)__ballot(own2)) - 1;
    if (lane == 0)
      vout[j] = (sp[j] << 10) | (unsigned int)(src * 16 + s2);  // 22-bit key
  }
}

// ---------------- Kernel 4: per-thread LDS accumulators (cannot spill) ----
// Each thread owns 31-word LDS slice: bins 0..14 at [b*2]={cnt|err<<16},
// [b*2+1]={keysum}. Odd stride 31 -> 2 lanes/bank (free tier).
// partials: [v][block], v = bin*4+{0=cnt,1=err,2=kk_lo32,3=kk_hi32}
__global__ __launch_bounds__(256) void k_bin(const unsigned int* __restrict__ keys,
                                             const unsigned int* __restrict__ vp,
                                             unsigned int* __restrict__ partials,
                                             unsigned int* __restrict__ dones,
                                             float* __restrict__ out, int n,
                                             Fracs fr) {
  __shared__ unsigned int acc[256 * 31];
  __shared__ unsigned int sT[16];
  __shared__ unsigned int blkCE[15];
  __shared__ unsigned long long blkKK[15];
  __shared__ double dacc[60];
  __shared__ unsigned int is_last;
  if (threadIdx.x < 16) {
    int i = threadIdx.x;
    float lo = (float)(vp[2 * i] + 1u) * 0x1p-20f;   // exact
    float hi = (float)(vp[2 * i + 1] + 1u) * 0x1p-20f;
    float f = fr.f[i];
    float e = lo * (1.0f - f) + hi * f;
    if (i == 15) e += 1e-6f;
    // T = smallest key with (key+0.5)*2^-20 > e
    double kd = (double)e * 1048576.0 - 0.5;
    int T = (int)floor(kd) + 1;
    while (T > 0 && ((float)(T - 1) + 0.5f) * 0x1p-20f > e) --T;
    while (((float)T + 0.5f) * 0x1p-20f <= e) ++T;
    sT[i] = (unsigned int)T;
  }
  if (threadIdx.x >= 64 && threadIdx.x < 79) blkCE[threadIdx.x - 64] = 0u;
  if (threadIdx.x >= 128 && threadIdx.x < 143) blkKK[threadIdx.x - 128] = 0ull;
  unsigned int* mine = &acc[threadIdx.x * 31];
#pragma unroll
  for (int i = 0; i < 30; ++i) mine[i] = 0u;
  __syncthreads();
  unsigned int tT[16];
#pragma unroll
  for (int j = 0; j < 16; ++j) tT[j] = sT[j];
  int stride = gridDim.x * 256;
  for (int i = blockIdx.x * 256 + threadIdx.x; i < n; i += stride) {
    unsigned int kp = keys[i];
    unsigned int key = kp & KEY_MAX;
    int less = 0;
#pragma unroll
    for (int j = 0; j < 16; ++j) less += (key >= tT[j]) ? 1 : 0;
    int bin = less - 1;  // valid 0..14
    if ((unsigned)bin < 15u) {
      unsigned int* p = mine + bin * 2;
      p[0] += 1u | ((kp >> 31) << 16);   // cnt | err<<16 (<=16 elems/thread)
      p[1] += key;                        // keysum (<=16*4.19M, fits u32)
    }
  }
  __syncthreads();
  int wid = threadIdx.x >> 6, lane = threadIdx.x & 63;
#pragma unroll
  for (int b = 0; b < 15; ++b) {
    unsigned int ce = mine[b * 2];
    unsigned long long kk = (unsigned long long)mine[b * 2 + 1];
    for (int off = 32; off > 0; off >>= 1) {
      ce += __shfl_xor(ce, off);
      kk += __shfl_xor(kk, off);
    }
    if (lane == 0) {
      atomicAdd(&blkCE[b], ce);
      atomicAdd(&blkKK[b], kk);
    }
  }
  __syncthreads();
  if (threadIdx.x < 60) {
    int b = threadIdx.x >> 2, comp = threadIdx.x & 3;
    unsigned int ce = blkCE[b];
    unsigned long long kk = blkKK[b];
    unsigned int v = (comp == 0) ? (ce & 0xFFFFu)
                   : (comp == 1) ? (ce >> 16)
                   : (comp == 2) ? (unsigned int)(kk & 0xFFFFFFFFull)
                                 : (unsigned int)(kk >> 32);
    partials[threadIdx.x * NBIN_BLOCKS + blockIdx.x] = v;
  }
  __threadfence();
  __syncthreads();
  if (threadIdx.x == 0)
    is_last = (atomicAdd(&dones[2], 1u) == (unsigned int)gridDim.x - 1u) ? 1u : 0u;
  __syncthreads();
  if (!is_last) return;
  __threadfence();
  for (int v = wid; v < 60; v += 4) {
    double s = 0.0;
    const unsigned int* pv = partials + v * NBIN_BLOCKS;
    for (int b2 = lane; b2 < NBIN_BLOCKS; b2 += 64) s += (double)pv[b2];
    for (int off = 32; off > 0; off >>= 1) s += __shfl_xor(s, off);
    if (lane == 0) dacc[v] = s;
  }
  __syncthreads();
  if (threadIdx.x == 0) {
    float g = 0.f;
    for (int b = 0; b < 15; ++b) {
      double cd = dacc[b * 4 + 0];
      double ed = dacc[b * 4 + 1];
      double kd = dacc[b * 4 + 3] * 4294967296.0 + dacc[b * 4 + 2];
      double safe = cd > 1.0 ? cd : 1.0;
      float u = (float)(((kd + 0.5 * cd) * (1.0 / 1048576.0)) / safe);
      float eb = (float)(ed / safe);
      float inner = 2.0f * exp2f(-u) - 1.0f;
      float s = (inner > 0.f) ? sqrtf(inner) : 0.f;
      float risk = 0.5f * (1.0f - s);
      g += (cd > 0.0) ? fabsf(eb - risk) : 0.f;
    }
    out[0] = g * (1.0f / 15.0f);
  }
}

extern "C" void kernel_launch(void* const* d_in, const int* in_sizes, int n_in,
                              void* d_out, int out_size, void* d_ws, size_t ws_size,
                              hipStream_t stream) {
  const float* logits = (const float*)d_in[0];
  const int* labels = (const int*)d_in[1];
  float* out = (float*)d_out;
  int n = in_sizes[1];  // labels count = number of rows

  char* ws = (char*)d_ws;
  size_t offKeys = 0;                                             // n*4 = 16MB
  size_t offHg = (size_t)n * 4;                                   // 2048*2048*4 = 16MB
  size_t offMerged = offHg + (size_t)NH2_BLOCKS * L1_UINTS * 4;   // 4096*4
  size_t offH2b = offMerged + (size_t)L1_BINS * 4;                // 32*1024*4
  size_t offDone = offH2b + (size_t)32 * L2_BINS * 4;             // 16B
  size_t offSelP = offDone + 16;                                  // 32*4
  size_t offSelR = offSelP + 128;                                 // 32*4
  size_t offV = offSelR + 128;                                    // 32*4
  size_t offPart = (offV + 128 + 255) & ~(size_t)255;             // 60*NBIN_BLOCKS*4

  unsigned int* keys = (unsigned int*)(ws + offKeys);
  unsigned int* histg = (unsigned int*)(ws + offHg);
  unsigned int* merged = (unsigned int*)(ws + offMerged);
  unsigned int* hist2 = (unsigned int*)(ws + offH2b);
  unsigned int* dones = (unsigned int*)(ws + offDone);
  unsigned int* selp = (unsigned int*)(ws + offSelP);
  unsigned int* selr = (unsigned int*)(ws + offSelR);
  unsigned int* vp = (unsigned int*)(ws + offV);
  unsigned int* part = (unsigned int*)(ws + offPart);

  // host-side quantile positions (f32, matching jnp.linspace/quantile math)
  Ranks rk;
  Fracs fr;
  float nm1 = (float)(n - 1);
  for (int i = 0; i < 16; ++i) {
    float q = (i == 15) ? 1.0f : (float)i * (1.0f / 15.0f);
    float idxf = q * nm1;
    float flo = floorf(idxf);
    unsigned int klo = (unsigned int)flo;
    unsigned int khi = (unsigned int)ceilf(idxf);
    unsigned int maxi = (unsigned int)(n - 1);
    if (klo > maxi) klo = maxi;
    if (khi > maxi) khi = maxi;
    rk.r[2 * i] = klo;
    rk.r[2 * i + 1] = khi;
    fr.f[i] = idxf - flo;
  }

  // 1) keys + per-block L1 hists (also zeroes done counters)
  k_h2<<<NH2_BLOCKS, 256, 0, stream>>>((const float4*)logits, labels, keys, histg, dones, n);
  // 2) merge hists; zero hist2; last block -> select L1 (12 bits)
  k_merge<<<NMG_BLOCKS, 256, 0, stream>>>(histg, merged, hist2, dones, selp, selr, rk);
  // 3) refine low 10 bits via LDS bin-map; last block -> select L2
  k_refine<<<NREF_BLOCKS, 256, 0, stream>>>(keys, selp, hist2, dones, selr, vp, n);
  // 4) binning via per-thread LDS accumulators + fused final
  k_bin<<<NBIN_BLOCKS, 256, 0, stream>>>(keys, vp, part, dones, out, n, fr);

  (void)n_in; (void)out_size; (void)ws_size;
}